// Round 12
// baseline (284.461 us; speedup 1.0000x reference)
//
#include <hip/hip_runtime.h>
#include <cstdint>
#include <cstddef>

// R17 (= R16 resubmit; previous round failed at container acquire, not in the
// kernel). Antiphase dual-group persistent GRU. 256 blocks x 512 thr, 1
// blk/CU (LDS>80KB => exactly 32 blocks/XCD). Each block owns 16 h-cols x 3
// gates and serves BOTH of its XCD's sample groups in antiphase:
//   wait_A -> half-step A -> arrive_A -> wait_B -> half-step B -> arrive_B
// Each group's barrier arrive is separated from its wait by the OTHER
// group's full half-step -> barrier/publish/RFO latency hidden by real work.
// Deadlock audit: identical per-block barrier order + wait-before-next-arrive
// bounds ticket skew to 1 round; monotonic targets replay-safe.
// W_hh LDS tile (48 rows x 512) shared by both groups. Formulas: 16-col
// staging/swizzle/A-slab from R13 (validated), wave-private epilogue/stash/
// warming from R15, gi-in-registers pre-GEMM from R12.

typedef __attribute__((ext_vector_type(8))) _Float16 f16x8;
typedef __attribute__((ext_vector_type(4))) float floatx4;

__device__ unsigned g_cnt[8 * 64];     // per-XCD registration tickets
__device__ unsigned g_gbar[16 * 64];   // per-group round tickets (padded)

// g_h[t]: [16 grp][32 cgrp][256 rows][16 cols] fp16 (cgrp slab = 8KB, block-
// private full lines). g_P[t]: [16 grp][32 cgrp][512] f32 (slab = 2KB).
__device__ __align__(256) _Float16 g_h[12][16 * 32 * 256 * 16];
__device__ __align__(256) float    g_P[12][16 * 32 * 512];

__device__ __forceinline__ float sigm_f(float v) { return 1.0f / (1.0f + __expf(-v)); }
__device__ __forceinline__ float tanh_f(float v) { return 2.0f / (1.0f + __expf(-2.0f * v)) - 1.0f; }

__device__ __forceinline__ void async16(void* lds, const void* g) {
    __builtin_amdgcn_global_load_lds(
        (const __attribute__((address_space(1))) void*)g,
        (__attribute__((address_space(3))) void*)lds, 16, 0, 0);
}

// Split barrier, 32 blocks/group/round. arrive: drain stores, post ticket
// (target valid in thread 0 only). wait: thread-0 poll + block barrier.
__device__ __forceinline__ unsigned group_arrive32(unsigned grp) {
    asm volatile("s_waitcnt vmcnt(0)" ::: "memory");
    __syncthreads();
    unsigned tgt = 0;
    if (threadIdx.x == 0) {
        unsigned t = __hip_atomic_fetch_add(&g_gbar[grp * 64], 1u, __ATOMIC_RELAXED,
                                            __HIP_MEMORY_SCOPE_AGENT);
        tgt = (t & ~31u) + 32u;
    }
    return tgt;
}
__device__ __forceinline__ void group_wait32(unsigned grp, unsigned tgt) {
    if (threadIdx.x == 0) {
        while (__hip_atomic_load(&g_gbar[grp * 64], __ATOMIC_RELAXED,
                                 __HIP_MEMORY_SCOPE_AGENT) < tgt)
            __builtin_amdgcn_s_sleep(1);
    }
    __syncthreads();
    asm volatile("" ::: "memory");
}

// ---------------- K0: casts + packing + a0 (unchanged, validated) ----------------
__global__ __launch_bounds__(256) void k0_prep(
    const float* __restrict__ z, const float* __restrict__ x,
    const float* __restrict__ x0, const float* __restrict__ W_ia,
    const float* __restrict__ b_ia, const float* __restrict__ W_ih,
    const float* __restrict__ W_hh, const float* __restrict__ W_h0,
    const float* __restrict__ W_out, const float* __restrict__ b_hh,
    _Float16* __restrict__ zx16, _Float16* __restrict__ wcat16,
    _Float16* __restrict__ whh16, float* __restrict__ pk, float* __restrict__ xbuf)
{
    const int ZX = 4096 * 256, WC = 2048 * 256, WH = 1536 * 512, PKN = 512, XB = 4096 * 2;
    const int total = ZX + WC + WH + PKN + XB;
    for (int idx = blockIdx.x * 256 + threadIdx.x; idx < total; idx += gridDim.x * 256) {
        if (idx < ZX) {
            int i = idx >> 8, k = idx & 255;
            float v = (k < 128) ? z[i * 128 + k] : x[i * 128 + (k - 128)];
            zx16[idx] = (_Float16)v;
        } else if (idx < ZX + WC) {
            int j = idx - ZX;
            int n = j >> 8, k = j & 255;
            float v = (n < 512) ? W_h0[n * 256 + k] : W_ih[(n - 512) * 258 + k];
            wcat16[j] = (_Float16)v;
        } else if (idx < ZX + WC + WH) {
            int j = idx - ZX - WC;
            whh16[j] = (_Float16)W_hh[j];
        } else if (idx < ZX + WC + WH + PKN) {
            int jc = idx - ZX - WC - WH;
            float* o = pk + jc * 12;
            o[0] = W_ih[jc * 258 + 256];          o[1] = W_ih[jc * 258 + 257];
            o[2] = W_ih[(512 + jc) * 258 + 256];  o[3] = W_ih[(512 + jc) * 258 + 257];
            o[4] = W_ih[(1024 + jc) * 258 + 256]; o[5] = W_ih[(1024 + jc) * 258 + 257];
            o[6] = b_hh[jc]; o[7] = b_hh[512 + jc]; o[8] = b_hh[1024 + jc];
            o[9] = W_out[jc]; o[10] = W_out[512 + jc]; o[11] = 0.f;
        } else {
            int j = idx - ZX - WC - WH - PKN;
            int i = j >> 1, d = j & 1;
            float s = b_ia[d];
            #pragma unroll
            for (int k2 = 0; k2 < 4; k2++) s += x0[i * 4 + k2] * W_ia[d * 4 + k2];
            xbuf[j] = s;
        }
    }
}

// ---------------- K2: antiphase dual-group persistent GRU ----------------
// LDS: B @0 (48 rows x 1024 = 48KB; pre-B 64x512=32KB overlap),
// hstore A @49152 / B @57344 (8KB each), xs A @65536 / B @67584 (2KB each),
// douts A @69632 / B @94208 (24KB each), dummy @118784, slot @119808.
// Request 119872 (>80KB => 1 blk/CU).
__global__ __launch_bounds__(512, 2) void k2_dual(
    const _Float16* __restrict__ zx16, const _Float16* __restrict__ wcat16,
    const _Float16* __restrict__ whh16, const float* __restrict__ pk,
    const float* __restrict__ xbuf, const float* __restrict__ b_h0,
    const float* __restrict__ b_ih, float* __restrict__ dout,
    const float* __restrict__ b_out)
{
    extern __shared__ __align__(16) char smem[];
    const uint32_t BOFF = 0, HST0 = 49152, XS0 = 65536, DOUTS0 = 69632,
                   DUM = 118784, SLO = 119808;
    const int tid = threadIdx.x;

    // ---- XCD discovery + registration (1 blk/CU => 32 blks/XCD) ----
    unsigned xcc;
    asm volatile("s_getreg_b32 %0, hwreg(HW_REG_XCC_ID)" : "=s"(xcc));
    xcc &= 7u;
    if (tid == 0) {
        unsigned s = __hip_atomic_fetch_add(&g_cnt[xcc * 64], 1u, __ATOMIC_RELAXED,
                                            __HIP_MEMORY_SCOPE_AGENT) & 31u;
        *(unsigned*)(smem + SLO) = s;
    }
    __syncthreads();
    const int cgrp = (int)*(volatile unsigned*)(smem + SLO);   // 0..31
    const int jc0 = cgrp * 16;

    const int wv = tid >> 6, lane = tid & 63;
    const int l15 = lane & 15, q2 = lane >> 4;

    // ---- warm g_h[0] slabs (both groups) ----
    if (wv == 0)
        async16(smem + DUM, (const char*)&g_h[0][0] + (size_t)(xcc * 2) * 262144 +
                            (size_t)cgrp * 8192 + (size_t)lane * 128);
    if (wv == 1)
        async16(smem + DUM, (const char*)&g_h[0][0] + (size_t)(xcc * 2 + 1) * 262144 +
                            (size_t)cgrp * 8192 + (size_t)lane * 128);

    // ---- stage pre-B: 64 rows x 256 fp16 (512B rows) [R13 verbatim] ----
    #pragma unroll
    for (int j2 = 0; j2 < 4; j2++) {
        int p = j2 * 8 + wv;
        int r0s = p * 2;
        int r = r0s + (lane >> 5);
        int s = lane & 31;
        int n = (r < 48) ? (512 + (r >> 4) * 512 + jc0 + (r & 15))
                         : (jc0 + (r - 48));
        const _Float16* src = wcat16 + (size_t)n * 256 + ((s ^ (r & 15)) << 3);
        async16(smem + (uint32_t)r0s * 512, src);
    }

    // ---- t-invariant params ----
    const int jc = jc0 + l15;
    const float4* pkp = (const float4*)(pk + (size_t)jc * 12);
    float4 p0v = pkp[0], p1v = pkp[1], p2v = pkp[2];
    float wo0 = p2v.y, wo1 = p2v.z;
    float bh0v = b_h0[jc];
    float bih0 = b_ih[jc], bih1 = b_ih[512 + jc], bih2 = b_ih[1024 + jc];
    float bo = b_out[tid & 1];

    uint32_t bbase[3];   // steady B (48 rows x 1024B) [R13 swizzle]
    #pragma unroll
    for (int g = 0; g < 3; g++) {
        int r = g * 16 + l15;
        bbase[g] = BOFF + (uint32_t)r * 1024 +
                   ((uint32_t)(q2 ^ (r & 3)) << 4) + ((uint32_t)((r >> 2) & 3) << 6);
    }
    uint32_t pb[4];      // pre-B (64 rows x 512B): 0..2 gates, 3 h0 [R13]
    #pragma unroll
    for (int sl = 0; sl < 4; sl++) {
        int r = (sl < 3) ? (sl * 16 + l15) : (48 + l15);
        pb[sl] = BOFF + (uint32_t)r * 512 +
                 ((uint32_t)(q2 ^ (r & 3)) << 4) + ((uint32_t)((r >> 2) & 3) << 6);
    }
    __syncthreads();   // pre-B staged (compiler drains vmcnt at barrier)

    // ---- pre-GEMM per group: K=256, gi -> regs, h0 -> hstore + publish ----
    float gi[2][2][3][4];
    unsigned tgt[2];
    #pragma unroll
    for (int g2 = 0; g2 < 2; g2++) {
        const int M0g = (int)(xcc * 2 + g2) * 256;
        const uint32_t hstB = HST0 + (uint32_t)g2 * 8192;
        const char* zp0 = (const char*)zx16 +
            (size_t)(M0g + (wv * 2 + 0) * 16 + l15) * 512 + (size_t)q2 * 16;
        const char* zp1 = (const char*)zx16 +
            (size_t)(M0g + (wv * 2 + 1) * 16 + l15) * 512 + (size_t)q2 * 16;
        floatx4 accP[2][4];
        #pragma unroll
        for (int mt = 0; mt < 2; mt++)
            #pragma unroll
            for (int sl = 0; sl < 4; sl++) accP[mt][sl] = (floatx4){0.f, 0.f, 0.f, 0.f};
        {
            f16x8 aqz[4][2];
            #define ALOADZ(S, KS) do { \
                aqz[S][0] = *(const f16x8*)(zp0 + (KS) * 64); \
                aqz[S][1] = *(const f16x8*)(zp1 + (KS) * 64); \
            } while (0)
            ALOADZ(0, 0); ALOADZ(1, 1); ALOADZ(2, 2);
            #pragma unroll
            for (int ks = 0; ks < 8; ks++) {
                if (ks < 5) { ALOADZ((ks + 3) & 3, ks + 3); }
                f16x8 a0 = aqz[ks & 3][0];
                f16x8 a1 = aqz[ks & 3][1];
                const uint32_t kadd = (uint32_t)((ks >> 2) << 8);
                const uint32_t kxor = (uint32_t)((ks & 3) << 6);
                #pragma unroll
                for (int sl = 0; sl < 4; sl++) {
                    f16x8 b = *(const f16x8*)(smem + ((pb[sl] + kadd) ^ kxor));
                    accP[0][sl] = __builtin_amdgcn_mfma_f32_16x16x32_f16(a0, b, accP[0][sl], 0, 0, 0);
                    accP[1][sl] = __builtin_amdgcn_mfma_f32_16x16x32_f16(a1, b, accP[1][sl], 0, 0, 0);
                }
            }
            #undef ALOADZ
        }
        #pragma unroll
        for (int mt = 0; mt < 2; mt++)
            #pragma unroll
            for (int reg = 0; reg < 4; reg++) {
                gi[g2][mt][0][reg] = accP[mt][0][reg] + bih0;
                gi[g2][mt][1][reg] = accP[mt][1][reg] + bih1;
                gi[g2][mt][2][reg] = accP[mt][2][reg] + bih2;
                int rl = wv * 32 + mt * 16 + q2 * 4 + reg;
                *(_Float16*)(smem + hstB + (uint32_t)(rl * 32 + l15 * 2)) =
                    (_Float16)(accP[mt][3][reg] + bh0v);
            }
        // publish h0 slice (wave-private rows; hstore just written by this wave)
        {
            int row = tid >> 1, half = tid & 1;
            const char* sl = smem + hstB + (uint32_t)(row * 32 + half * 16);
            char* gd = (char*)&g_h[0][0] + (size_t)(xcc * 2 + g2) * 262144 +
                       (size_t)cgrp * 8192 + (size_t)row * 32 + (size_t)half * 16;
            *(f16x8*)gd = *(const f16x8*)sl;
        }
    }
    __syncthreads();   // all pre-B LDS reads complete before W_hh overwrites

    // ---- stage W_hh (48 rows x 512 = 48KB) [R13 verbatim] ----
    #pragma unroll
    for (int j = 0; j < 6; j++) {
        int r = j * 8 + wv;
        int n = (r >> 4) * 512 + jc0 + (r & 15);
        const _Float16* src = whh16 + (size_t)n * 512 + ((lane ^ (r & 15)) << 3);
        async16(smem + BOFF + (uint32_t)r * 1024, src);
    }
    tgt[0] = group_arrive32(xcc * 2);       // drains W_hh stage + h0 publishes
    tgt[1] = group_arrive32(xcc * 2 + 1);

    // ---- 12-step loop, antiphase halves ----
    #pragma unroll 1
    for (int t = 0; t < 12; t++) {
        #pragma unroll
        for (int g2 = 0; g2 < 2; g2++) {
            const unsigned grp = xcc * 2 + (unsigned)g2;
            const int M0g = (int)grp * 256;
            const uint32_t hstB = HST0 + (uint32_t)g2 * 8192;
            const uint32_t xsB  = XS0 + (uint32_t)g2 * 2048;
            float* dstash = (float*)(smem + DOUTS0 + (uint32_t)g2 * 24576);
            const size_t hGB = (size_t)grp * 262144;
            const size_t pGF = (size_t)grp * 16384;

            group_wait32(grp, tgt[g2]);   // h[t] of this group ready

            // warming: own h[t+1] slab (8KB) + own P[t] slab (2KB)
            if (t < 11 && wv == 0)
                async16(smem + DUM, (const char*)&g_h[t + 1][0] + hGB +
                                    (size_t)cgrp * 8192 + (size_t)lane * 128);
            if (wv == 2)
                async16(smem + DUM, (const char*)(&g_P[t][0] + pGF + (size_t)cgrp * 512) +
                                    (size_t)lane * 32);

            // prologue P-loads issued early (summed after GEMM)
            float pv[32];
            if (t > 0) {
                const float* pb2 = &g_P[t - 1][0] + pGF + tid;
                #pragma unroll
                for (int c = 0; c < 32; c++) pv[c] = pb2[c * 512];
            }

            // GEMM: K=512, A from g_h[t] block-major slabs [R13 addressing]
            const char* hb = (const char*)&g_h[t][0] + hGB +
                             (size_t)(q2 >> 1) * 8192 + (size_t)(q2 & 1) * 16;
            const char* rp0 = hb + (size_t)((wv * 2 + 0) * 16 + l15) * 32;
            const char* rp1 = hb + (size_t)((wv * 2 + 1) * 16 + l15) * 32;
            floatx4 acc[2][3];
            #pragma unroll
            for (int mt = 0; mt < 2; mt++)
                #pragma unroll
                for (int g = 0; g < 3; g++) acc[mt][g] = (floatx4){0.f, 0.f, 0.f, 0.f};
            {
                f16x8 aq[4][2];
                #define ALOAD(S, KS) do { \
                    aq[S][0] = *(const f16x8*)(rp0 + (size_t)(KS) * 16384); \
                    aq[S][1] = *(const f16x8*)(rp1 + (size_t)(KS) * 16384); \
                } while (0)
                ALOAD(0, 0); ALOAD(1, 1); ALOAD(2, 2);
                #pragma unroll
                for (int ks = 0; ks < 16; ks++) {
                    if (ks < 13) { ALOAD((ks + 3) & 3, ks + 3); }
                    f16x8 a0 = aq[ks & 3][0];
                    f16x8 a1 = aq[ks & 3][1];
                    const uint32_t kadd = (uint32_t)((ks >> 2) << 8);
                    const uint32_t kxor = (uint32_t)((ks & 3) << 6);
                    #pragma unroll
                    for (int g = 0; g < 3; g++) {
                        f16x8 b = *(const f16x8*)(smem + ((bbase[g] + kadd) ^ kxor));
                        acc[0][g] = __builtin_amdgcn_mfma_f32_16x16x32_f16(a0, b, acc[0][g], 0, 0, 0);
                        acc[1][g] = __builtin_amdgcn_mfma_f32_16x16x32_f16(a1, b, acc[1][g], 0, 0, 0);
                    }
                }
                #undef ALOAD
            }

            // prologue finish (wave-private): x_t; stash out_{t-1}
            {
                float v;
                if (t == 0) {
                    v = xbuf[(size_t)(M0g + (tid >> 1)) * 2 + (tid & 1)];
                } else {
                    v = bo;
                    #pragma unroll
                    for (int c = 0; c < 32; c++) v += pv[c];
                    dstash[wv * 768 + (t - 1) * 64 + lane] = v;
                }
                *(float*)(smem + xsB + (uint32_t)tid * 4) = v;
            }

            // epilogue (wave-private rows): gates, hn -> hstore, po -> g_P[t]
            #pragma unroll
            for (int mt = 0; mt < 2; mt++) {
                float po0[4], po1[4];
                #pragma unroll
                for (int reg = 0; reg < 4; reg++) {
                    int rl = wv * 32 + mt * 16 + q2 * 4 + reg;
                    float2 xv = *(const float2*)(smem + xsB + (uint32_t)rl * 8);
                    _Float16* hp = (_Float16*)(smem + hstB + (uint32_t)(rl * 32 + l15 * 2));
                    float hold = (float)hp[0];
                    float r  = sigm_f(gi[g2][mt][0][reg] + p0v.x * xv.x + p0v.y * xv.y + acc[mt][0][reg] + p1v.z);
                    float u  = sigm_f(gi[g2][mt][1][reg] + p0v.z * xv.x + p0v.w * xv.y + acc[mt][1][reg] + p1v.w);
                    float nn = tanh_f(gi[g2][mt][2][reg] + p1v.x * xv.x + p1v.y * xv.y + r * (acc[mt][2][reg] + p2v.x));
                    float hn = (1.f - u) * nn + u * hold;
                    hp[0] = (_Float16)hn;
                    po0[reg] = hn * wo0;
                    po1[reg] = hn * wo1;
                }
                #pragma unroll
                for (int m = 1; m < 16; m <<= 1)
                    #pragma unroll
                    for (int reg = 0; reg < 4; reg++) {
                        po0[reg] += __shfl_xor(po0[reg], m);
                        po1[reg] += __shfl_xor(po1[reg], m);
                    }
                if (l15 == 0) {
                    #pragma unroll
                    for (int reg = 0; reg < 4; reg++) {
                        int rl = wv * 32 + mt * 16 + q2 * 4 + reg;
                        float* pp = &g_P[t][0] + pGF + (size_t)cgrp * 512 + (size_t)rl * 2;
                        *(float2*)pp = make_float2(po0[reg], po1[reg]);
                    }
                }
            }

            // publish h[t+1] slab (wave-private rows, block-contiguous)
            if (t < 11) {
                int row = tid >> 1, half = tid & 1;
                const char* sl = smem + hstB + (uint32_t)(row * 32 + half * 16);
                char* gd = (char*)&g_h[t + 1][0] + hGB + (size_t)cgrp * 8192 +
                           (size_t)row * 32 + (size_t)half * 16;
                *(f16x8*)gd = *(const f16x8*)sl;
            }
            tgt[g2] = group_arrive32(grp);
        }
    }

    // ---- final: out_11 for both groups, then dout flush (cgrp 0 only) ----
    #pragma unroll
    for (int g2 = 0; g2 < 2; g2++) {
        const unsigned grp = xcc * 2 + (unsigned)g2;
        group_wait32(grp, tgt[g2]);
        if (cgrp == 0) {
            const float* pb2 = &g_P[11][0] + (size_t)grp * 16384 + tid;
            float v = bo;
            #pragma unroll
            for (int c = 0; c < 32; c++) v += pb2[c * 512];
            float* dstash = (float*)(smem + DOUTS0 + (uint32_t)g2 * 24576);
            dstash[wv * 768 + 11 * 64 + lane] = v;
        }
    }
    if (cgrp == 0) {
        #pragma unroll
        for (int g2 = 0; g2 < 2; g2++) {
            float* dstash = (float*)(smem + DOUTS0 + (uint32_t)g2 * 24576);
            size_t i = (size_t)((int)(xcc * 2 + g2) * 256 + wv * 32 + (lane >> 1));
            int d = lane & 1;
            #pragma unroll
            for (int tt = 0; tt < 12; tt++)
                dout[(i * 12 + tt) * 2 + d] = dstash[wv * 768 + tt * 64 + lane];
        }
    }
}

extern "C" void kernel_launch(void* const* d_in, const int* in_sizes, int n_in,
                              void* d_out, int out_size, void* d_ws, size_t ws_size,
                              hipStream_t stream)
{
    const float* z     = (const float*)d_in[0];
    const float* x     = (const float*)d_in[1];
    const float* x0    = (const float*)d_in[2];
    const float* W_ia  = (const float*)d_in[3];
    const float* b_ia  = (const float*)d_in[4];
    const float* W_h0  = (const float*)d_in[5];
    const float* b_h0  = (const float*)d_in[6];
    const float* W_ih  = (const float*)d_in[7];
    const float* b_ih  = (const float*)d_in[8];
    const float* W_hh  = (const float*)d_in[9];
    const float* b_hh  = (const float*)d_in[10];
    const float* W_out = (const float*)d_in[11];
    const float* b_out = (const float*)d_in[12];
    float* dout = (float*)d_out;

    char* ws = (char*)d_ws;
    _Float16* zx16   = (_Float16*)(ws + 20971520);   // 2 MiB
    _Float16* wcat16 = (_Float16*)(ws + 23068672);   // 1 MiB
    _Float16* whh16  = (_Float16*)(ws + 24117248);   // 1.5 MiB
    float*    pk     = (float*)(ws + 25690112);      // 24 KiB
    float*    xbuf   = (float*)(ws + 25714688);      // 32 KiB

    static bool s_attr_done = false;
    if (!s_attr_done) {
        hipFuncSetAttribute((const void*)k2_dual,
                            hipFuncAttributeMaxDynamicSharedMemorySize, 119872);
        s_attr_done = true;
    }

    k0_prep<<<2048, 256, 0, stream>>>(z, x, x0, W_ia, b_ia, W_ih, W_hh, W_h0,
                                      W_out, b_hh, zx16, wcat16, whh16, pk, xbuf);
    k2_dual<<<256, 512, 119872, stream>>>(zx16, wcat16, whh16, pk, xbuf,
                                          b_h0, b_ih, dout, b_out);
}